// Round 4
// baseline (191.605 us; speedup 1.0000x reference)
//
#include <hip/hip_runtime.h>

// YOLO-v1 loss forward, S=7, B=2, C=20, bs=16384.
// R16 = occupancy probe of the ~3.3 TB/s read wall. Evidence:
//   R15 (NT, pipelined): kernel <=~58 us, 3.3 TB/s  | R13 (no-NT): 75 us, 2.57
//   -> NT worth +30% (read-allocate traffic confirmed). Pipeline: no effect.
//   fills 6.6 TB/s pure-write; m13 copy 3.15 read || 3.15 write. Ambiguous:
//   symmetric-bus model says pure-read ~6.3 possible; MSHR model (~40
//   lines/CU x 128B / 900cy x 256CU = 3.3 TB/s) says we're done.
// Probe: raise waves/CU 5 -> 8 by halving LDS (ONE 15.36 KB buffer, stage
// P then L through it) and doubling NBLOCKS to 2560. NT register staging and
// prefetch schedule kept. Reduction association changes slightly (2560
// partials) — also probes the harness absmax tolerance.
// Predict: concurrency-limited -> ~40 us kernel / ~172 total; hard wall ->
// unchanged ~58/190 and we declare roofline.

#define SS 7
#define CELL_STRIDE 30                         // 5*B + C floats per cell
#define TILE_CELLS 128                         // per wave-private tile
#define TILE_FLOATS (TILE_CELLS * CELL_STRIDE) // 3840 floats = 15360 B (ONE buffer)
#define NBLOCKS 2560                           // 8 waves/CU resident (VGPR-capped)

typedef float vfloat4 __attribute__((ext_vector_type(4)));

// LDS writes complete before cross-lane reads. lgkmcnt only — global
// prefetch loads must stay in flight across this point.
__device__ __forceinline__ void lds_write_read_fence() {
    asm volatile("s_waitcnt lgkmcnt(0)" ::: "memory");
    __builtin_amdgcn_sched_barrier(0);
    __builtin_amdgcn_wave_barrier();
}

// Compiler-order barrier: this phase's ds_reads stay before the next phase's
// ds_writes. HW side is safe (same-wave DS ops execute in order).
__device__ __forceinline__ void tile_boundary_fence() {
    asm volatile("" ::: "memory");
    __builtin_amdgcn_wave_barrier();
}

__device__ __forceinline__ vfloat4 nt_load_f4(const vfloat4* p) {
    return __builtin_nontemporal_load(p);
}

// 15 NT dwordx4, wave-contiguous (full 128B lines per instruction -> NT-safe)
__device__ __forceinline__ void load_buf(const float* __restrict__ src,
                                         size_t fbase, int lane, vfloat4* d) {
    const vfloat4* g = reinterpret_cast<const vfloat4*>(src + fbase);
    #pragma unroll
    for (int k = 0; k < 15; ++k) d[k] = nt_load_f4(g + lane + 64 * k);
}

__device__ __forceinline__ float yolo_cell_loss(const float* pv, const float* lv, int cell) {
    const int rem = cell % (SS * SS);
    const float gx = (float)(rem % SS);   // meshgrid 'xy': x = col
    const float gy = (float)(rem / SS);   // y = row

    const float obj = lv[4];
    const float lx = lv[0], ly = lv[1], lw = lv[2], lh = lv[3];
    const float l_cx = (gx + lx) / 7.0f;
    const float l_cy = (gy + ly) / 7.0f;
    const float l_minx = l_cx - lw * 0.5f, l_maxx = l_cx + lw * 0.5f;
    const float l_miny = l_cy - lh * 0.5f, l_maxy = l_cy + lh * 0.5f;
    const float area_l = lw * lh;

    float iou[2], box_err[2], conf[2];
    #pragma unroll
    for (int b = 0; b < 2; ++b) {
        const float px = pv[5 * b + 0], py = pv[5 * b + 1];
        const float pw = pv[5 * b + 2], ph = pv[5 * b + 3];
        conf[b] = pv[5 * b + 4];
        const float p_cx = (gx + px) / 7.0f;
        const float p_cy = (gy + py) / 7.0f;
        const float p_minx = p_cx - pw * 0.5f, p_maxx = p_cx + pw * 0.5f;
        const float p_miny = p_cy - ph * 0.5f, p_maxy = p_cy + ph * 0.5f;
        float iw = fminf(p_maxx, l_maxx) - fmaxf(p_minx, l_minx);
        float ih = fminf(p_maxy, l_maxy) - fmaxf(p_miny, l_miny);
        iw = fmaxf(iw, 0.0f); ih = fmaxf(ih, 0.0f);
        const float inter = iw * ih;
        const float uni = pw * ph + area_l - inter + 1e-10f;
        iou[b] = inter / uni;
        const float dx = px - lx, dy = py - ly;
        const float dw = sqrtf(pw) - sqrtf(lw);
        const float dh = sqrtf(ph) - sqrtf(lh);
        box_err[b] = (dx * dx + dy * dy) + (dw * dw + dh * dh);
    }

    // argmax tie-break: first max wins -> box 1 only if strictly greater
    const int r = (iou[1] > iou[0]) ? 1 : 0;
    const float cr = conf[r], cn = conf[1 - r];

    float loss = obj * (5.0f * box_err[r] + (cr - iou[r]) * (cr - iou[r]));
    loss += 0.5f * ((1.0f - obj) * cr * cr + cn * cn);

    float cls = 0.0f;
    #pragma unroll
    for (int k = 10; k < 30; ++k) {
        const float d = pv[k] - lv[k];
        cls += d * d;
    }
    loss += obj * cls;
    return loss;
}

// extract ONE cell (HALF=0: floats [60*lane,+30); HALF=1: [60*lane+30,+30))
// 8 ds_read_b128 per cell; boundary v4 (idx 15*lane+7) read by both halves.
template <int HALF>
__device__ __forceinline__ void extract_cell(const vfloat4* sh4, int lane, float* c) {
    #pragma unroll
    for (int j = 0; j < 8; ++j) {
        const int v4i = HALF * 7 + j;            // 0..7 or 7..14
        const vfloat4 v = sh4[15 * lane + v4i];
        #pragma unroll
        for (int q = 0; q < 4; ++q) {
            const int f = 4 * v4i + q - 30 * HALF;  // compile-time
            if (f >= 0 && f < 30) c[f] = v[q];
        }
    }
}

__global__ __launch_bounds__(64, 1) void yolo_loss_partial(
    const float* __restrict__ preds,
    const float* __restrict__ labels,
    float* __restrict__ partial,
    int ntiles, float inv_bs, int use_atomic)
{
    __shared__ float sh[TILE_FLOATS];        // single 15360 B buffer (P then L)
    vfloat4* sh4 = reinterpret_cast<vfloat4*>(sh);
    const int lane = threadIdx.x;            // 0..63, single-wave block

    float acc = 0.0f;

    int tile = blockIdx.x;
    vfloat4 t[15], u[15];
    if (tile < ntiles) {
        load_buf(preds,  (size_t)tile * TILE_FLOATS, lane, t);
        load_buf(labels, (size_t)tile * TILE_FLOATS, lane, u);
    }

    while (tile < ntiles) {
        const int next = tile + NBLOCKS;

        // ---- P stage: t -> LDS, extract both cells (u stays in flight) ----
        #pragma unroll
        for (int k = 0; k < 15; ++k) sh4[lane + 64 * k] = t[k];
        lds_write_read_fence();              // lgkm only — vmcnt NOT drained
        float pva[CELL_STRIDE], pvb[CELL_STRIDE];
        extract_cell<0>(sh4, lane, pva);
        extract_cell<1>(sh4, lane, pvb);
        tile_boundary_fence();               // P reads before L writes

        // ---- L stage: u -> same LDS buffer ----
        #pragma unroll
        for (int k = 0; k < 15; ++k) sh4[lane + 64 * k] = u[k];
        lds_write_read_fence();

        // prefetch next tile's P (t is dead); stays in flight through compute
        if (next < ntiles)
            load_buf(preds, (size_t)next * TILE_FLOATS, lane, t);
        __builtin_amdgcn_sched_barrier(0);   // pin loads before the ds_reads

        float lva[CELL_STRIDE], lvb[CELL_STRIDE];
        extract_cell<0>(sh4, lane, lva);
        extract_cell<1>(sh4, lane, lvb);
        tile_boundary_fence();               // L reads before next P writes

        const int cellA = tile * TILE_CELLS + 2 * lane;
        acc += yolo_cell_loss(pva, lva, cellA);
        acc += yolo_cell_loss(pvb, lvb, cellA + 1);

        // prefetch next tile's L (u is dead)
        if (next < ntiles)
            load_buf(labels, (size_t)next * TILE_FLOATS, lane, u);

        tile = next;
    }

    acc *= inv_bs;

    // single-wave shuffle reduction
    #pragma unroll
    for (int off = 32; off > 0; off >>= 1)
        acc += __shfl_down(acc, off, 64);

    if (lane == 0) {
        if (use_atomic) atomicAdd(partial, acc);     // fallback: partial==out
        else            partial[blockIdx.x] = acc;
    }
}

__global__ __launch_bounds__(256) void yolo_reduce(
    const float* __restrict__ partial, float* __restrict__ out, int n)
{
    float acc = 0.0f;
    for (int i = threadIdx.x; i < n; i += 256) acc += partial[i];
    #pragma unroll
    for (int off = 32; off > 0; off >>= 1)
        acc += __shfl_down(acc, off, 64);
    __shared__ float wsum[4];
    const int lane = threadIdx.x & 63;
    const int wid  = threadIdx.x >> 6;
    if (lane == 0) wsum[wid] = acc;
    __syncthreads();
    if (threadIdx.x == 0) out[0] = wsum[0] + wsum[1] + wsum[2] + wsum[3];
}

__global__ void yolo_zero_out(float* out) {
    if (threadIdx.x == 0) out[0] = 0.0f;
}

extern "C" void kernel_launch(void* const* d_in, const int* in_sizes, int n_in,
                              void* d_out, int out_size, void* d_ws, size_t ws_size,
                              hipStream_t stream) {
    const float* preds  = (const float*)d_in[0];
    const float* labels = (const float*)d_in[1];
    float* out = (float*)d_out;

    const int ncells = in_sizes[0] / CELL_STRIDE;        // 802816 (divisible by 128)
    const int ntiles = ncells / TILE_CELLS;              // 6272
    const int bs     = ncells / (SS * SS);               // 16384
    const float inv_bs = 1.0f / (float)bs;

    if (ws_size >= NBLOCKS * sizeof(float)) {
        float* partial = (float*)d_ws;
        yolo_loss_partial<<<NBLOCKS, 64, 0, stream>>>(preds, labels, partial,
                                                      ntiles, inv_bs, 0);
        yolo_reduce<<<1, 256, 0, stream>>>(partial, out, NBLOCKS);
    } else {
        yolo_zero_out<<<1, 64, 0, stream>>>(out);
        yolo_loss_partial<<<NBLOCKS, 64, 0, stream>>>(preds, labels, out,
                                                      ntiles, inv_bs, 1);
    }
}